// Round 2
// baseline (3367.718 us; speedup 1.0000x reference)
//
#include <hip/hip_runtime.h>

#define NN   4096   // nodes
#define ED   64     // embed dim
#define DIN  256    // in_dim
#define DOUT 256    // out_dim
#define NB   32     // batch

#define BM 64       // node rows per block in k_gcn
#define BK 32       // k-chunk (m dimension) staged in LDS

__device__ __forceinline__ void fma4(float4& d, float s, const float4& v) {
    d.x = fmaf(s, v.x, d.x);
    d.y = fmaf(s, v.y, d.y);
    d.z = fmaf(s, v.z, d.z);
    d.w = fmaf(s, v.w, d.w);
}

// ---------------- K1: E = emb_table[node_ids] ----------------
__global__ void k_gather(const float* __restrict__ emb, const int* __restrict__ ids,
                         float* __restrict__ E) {
    int n = blockIdx.x;
    int e = threadIdx.x;          // 64 threads
    int id = ids[n];
    id = id < 0 ? 0 : (id >= NN ? NN - 1 : id);   // clamp: never fault
    E[(size_t)n * ED + e] = emb[(size_t)id * ED + e];
}

// ---------------- K2a: logits = relu(E E^T), 64x64 tile ----------------
__global__ __launch_bounds__(256) void k_logits(const float* __restrict__ E,
                                                float* __restrict__ logits) {
    __shared__ __align__(16) float Ea[ED][64 + 4];   // transposed: Ea[k][row]
    __shared__ __align__(16) float Eb[ED][64 + 4];
    const int tid = threadIdx.x;
    const int ty = tid >> 4, tx = tid & 15;
    const int rb = blockIdx.x, cb = blockIdx.y;

    #pragma unroll
    for (int k = 0; k < 4; ++k) {
        int l = tid + k * 256;          // 0..1023
        int row = l >> 4;               // 0..63
        int kq = (l & 15) * 4;          // 0..60
        float4 va = *(const float4*)&E[(size_t)(rb * 64 + row) * ED + kq];
        Ea[kq + 0][row] = va.x; Ea[kq + 1][row] = va.y;
        Ea[kq + 2][row] = va.z; Ea[kq + 3][row] = va.w;
        float4 vb = *(const float4*)&E[(size_t)(cb * 64 + row) * ED + kq];
        Eb[kq + 0][row] = vb.x; Eb[kq + 1][row] = vb.y;
        Eb[kq + 2][row] = vb.z; Eb[kq + 3][row] = vb.w;
    }
    __syncthreads();

    float4 acc[4] = {};                 // acc[i] = row ty*4+i, cols tx*4..tx*4+3
    #pragma unroll
    for (int k = 0; k < ED; ++k) {
        float4 ar = *(const float4*)&Ea[k][ty * 4];
        float4 br = *(const float4*)&Eb[k][tx * 4];
        fma4(acc[0], ar.x, br);
        fma4(acc[1], ar.y, br);
        fma4(acc[2], ar.z, br);
        fma4(acc[3], ar.w, br);
    }

    #pragma unroll
    for (int i = 0; i < 4; ++i) {
        float4 v = acc[i];
        v.x = fmaxf(v.x, 0.f); v.y = fmaxf(v.y, 0.f);
        v.z = fmaxf(v.z, 0.f); v.w = fmaxf(v.w, 0.f);
        size_t n = (size_t)(rb * 64 + ty * 4 + i);
        *(float4*)&logits[n * NN + cb * 64 + tx * 4] = v;
    }
}

// ---------------- K2b: in-place row softmax ----------------
__global__ __launch_bounds__(256) void k_softmax(float* __restrict__ adj) {
    __shared__ float red[256];
    const int tid = threadIdx.x;
    const size_t base = (size_t)blockIdx.x * NN;

    float4 v[4];
    float mx = 0.0f;                    // relu output >= 0, so row max >= 0
    #pragma unroll
    for (int k = 0; k < 4; ++k) {
        v[k] = *(const float4*)&adj[base + tid * 4 + (size_t)k * 1024];
        mx = fmaxf(mx, fmaxf(fmaxf(v[k].x, v[k].y), fmaxf(v[k].z, v[k].w)));
    }
    red[tid] = mx; __syncthreads();
    for (int off = 128; off > 0; off >>= 1) {
        if (tid < off) red[tid] = fmaxf(red[tid], red[tid + off]);
        __syncthreads();
    }
    mx = red[0];
    __syncthreads();

    float s = 0.f;
    #pragma unroll
    for (int k = 0; k < 4; ++k) {
        v[k].x = expf(v[k].x - mx); v[k].y = expf(v[k].y - mx);
        v[k].z = expf(v[k].z - mx); v[k].w = expf(v[k].w - mx);
        s += v[k].x + v[k].y + v[k].z + v[k].w;
    }
    red[tid] = s; __syncthreads();
    for (int off = 128; off > 0; off >>= 1) {
        if (tid < off) red[tid] += red[tid + off];
        __syncthreads();
    }
    const float inv = 1.0f / red[0];

    #pragma unroll
    for (int k = 0; k < 4; ++k) {
        v[k].x *= inv; v[k].y *= inv; v[k].z *= inv; v[k].w *= inv;
        *(float4*)&adj[base + tid * 4 + (size_t)k * 1024] = v[k];
    }
}

// ---------------- K3: out = relu((adj @ x) @ W + b), fused ----------------
// grid (NN/BM, NB), 256 threads = 16 row-groups x 16 col-groups
// thread micro-tile: 4 rows x 16 cols (4x float4)
__global__ __launch_bounds__(256, 2) void k_gcn(const float* __restrict__ adj,
                                                const float* __restrict__ x,
                                                const float* __restrict__ W,
                                                const float* __restrict__ bias,
                                                float* __restrict__ out) {
    __shared__ __align__(16) union SMem {
        struct { float adjT[BK][BM + 4]; float xt[BK][DIN]; } s;  // 8704 + 32768 B
        float h[BM][DIN + 4];                                     // 66560 B
    } u;

    const int tid = threadIdx.x;
    const int ty = tid >> 4, tx = tid & 15;
    const int rb = blockIdx.x;          // node row-block
    const int b  = blockIdx.y;          // batch
    const float* xb = x + (size_t)b * NN * DIN;

    float4 acc[4][4] = {};              // [row i][col-block j]

    for (int k0 = 0; k0 < NN; k0 += BK) {
        // stage adj tile, transposed -> adjT[m][n]
        #pragma unroll
        for (int k = 0; k < 2; ++k) {
            int l = tid + k * 256;          // 0..511
            int n = l >> 3;                 // 0..63
            int mq = (l & 7) * 4;           // 0..28
            float4 v = *(const float4*)&adj[(size_t)(rb * BM + n) * NN + k0 + mq];
            u.s.adjT[mq + 0][n] = v.x; u.s.adjT[mq + 1][n] = v.y;
            u.s.adjT[mq + 2][n] = v.z; u.s.adjT[mq + 3][n] = v.w;
        }
        // stage x tile (row-major, naturally aligned float4s)
        #pragma unroll
        for (int k = 0; k < 8; ++k) {
            int l = tid + k * 256;          // 0..2047
            int m = l >> 6;                 // 0..31
            int dq = (l & 63) * 4;          // 0..252
            *(float4*)&u.s.xt[m][dq] = *(const float4*)&xb[(size_t)(k0 + m) * DIN + dq];
        }
        __syncthreads();

        #pragma unroll 8
        for (int m = 0; m < BK; ++m) {
            float4 a  = *(const float4*)&u.s.adjT[m][ty * 4];
            float4 x0 = *(const float4*)&u.s.xt[m][tx * 4];
            float4 x1 = *(const float4*)&u.s.xt[m][tx * 4 + 64];
            float4 x2 = *(const float4*)&u.s.xt[m][tx * 4 + 128];
            float4 x3 = *(const float4*)&u.s.xt[m][tx * 4 + 192];
            fma4(acc[0][0], a.x, x0); fma4(acc[0][1], a.x, x1);
            fma4(acc[0][2], a.x, x2); fma4(acc[0][3], a.x, x3);
            fma4(acc[1][0], a.y, x0); fma4(acc[1][1], a.y, x1);
            fma4(acc[1][2], a.y, x2); fma4(acc[1][3], a.y, x3);
            fma4(acc[2][0], a.z, x0); fma4(acc[2][1], a.z, x1);
            fma4(acc[2][2], a.z, x2); fma4(acc[2][3], a.z, x3);
            fma4(acc[3][0], a.w, x0); fma4(acc[3][1], a.w, x1);
            fma4(acc[3][2], a.w, x2); fma4(acc[3][3], a.w, x3);
        }
        __syncthreads();
    }

    // dump h tile to LDS (reuse the union)
    #pragma unroll
    for (int i = 0; i < 4; ++i)
        #pragma unroll
        for (int j = 0; j < 4; ++j)
            *(float4*)&u.h[ty * 4 + i][tx * 4 + j * 64] = acc[i][j];
    __syncthreads();

    // phase B: out = relu(h @ W + bias)
    float4 ob[4][4];
    #pragma unroll
    for (int j = 0; j < 4; ++j) {
        float4 bj = *(const float4*)&bias[tx * 4 + j * 64];
        ob[0][j] = bj; ob[1][j] = bj; ob[2][j] = bj; ob[3][j] = bj;
    }
    #pragma unroll 4
    for (int d = 0; d < DIN; ++d) {
        float h0 = u.h[ty * 4 + 0][d];
        float h1 = u.h[ty * 4 + 1][d];
        float h2 = u.h[ty * 4 + 2][d];
        float h3 = u.h[ty * 4 + 3][d];
        const float* wr = &W[(size_t)d * DOUT];
        float4 w0 = *(const float4*)&wr[tx * 4];
        float4 w1 = *(const float4*)&wr[tx * 4 + 64];
        float4 w2 = *(const float4*)&wr[tx * 4 + 128];
        float4 w3 = *(const float4*)&wr[tx * 4 + 192];
        fma4(ob[0][0], h0, w0); fma4(ob[0][1], h0, w1); fma4(ob[0][2], h0, w2); fma4(ob[0][3], h0, w3);
        fma4(ob[1][0], h1, w0); fma4(ob[1][1], h1, w1); fma4(ob[1][2], h1, w2); fma4(ob[1][3], h1, w3);
        fma4(ob[2][0], h2, w0); fma4(ob[2][1], h2, w1); fma4(ob[2][2], h2, w2); fma4(ob[2][3], h2, w3);
        fma4(ob[3][0], h3, w0); fma4(ob[3][1], h3, w1); fma4(ob[3][2], h3, w2); fma4(ob[3][3], h3, w3);
    }

    #pragma unroll
    for (int i = 0; i < 4; ++i) {
        size_t row = (size_t)b * NN + (size_t)(rb * BM + ty * 4 + i);
        #pragma unroll
        for (int j = 0; j < 4; ++j) {
            float4 v = ob[i][j];
            v.x = fmaxf(v.x, 0.f); v.y = fmaxf(v.y, 0.f);
            v.z = fmaxf(v.z, 0.f); v.w = fmaxf(v.w, 0.f);
            *(float4*)&out[row * DOUT + tx * 4 + j * 64] = v;
        }
    }
}

extern "C" void kernel_launch(void* const* d_in, const int* in_sizes, int n_in,
                              void* d_out, int out_size, void* d_ws, size_t ws_size,
                              hipStream_t stream) {
    const float* x    = (const float*)d_in[0];
    const int*   ids  = (const int*)d_in[1];
    const float* emb  = (const float*)d_in[2];
    const float* W    = (const float*)d_in[3];
    const float* bias = (const float*)d_in[4];
    float* out = (float*)d_out;

    float* adj = (float*)d_ws;                       // NN*NN f32 = 64 MB
    float* E   = adj + (size_t)NN * NN;              // NN*ED f32 = 1 MB

    k_gather  <<<NN, ED, 0, stream>>>(emb, ids, E);
    k_logits  <<<dim3(NN / 64, NN / 64), 256, 0, stream>>>(E, adj);
    k_softmax <<<NN, 256, 0, stream>>>(adj);
    k_gcn     <<<dim3(NN / BM, NB), 256, 0, stream>>>(adj, x, W, bias, out);
}

// Round 5
// 423.875 us; speedup vs baseline: 7.9451x; 7.9451x over previous
//
#include <hip/hip_runtime.h>

#define NN   4096   // nodes
#define ED   64     // embed dim
#define DIN  256    // in_dim
#define DOUT 256    // out_dim
#define NB   32     // batch

typedef __attribute__((ext_vector_type(8))) short bf16x8;
typedef __attribute__((ext_vector_type(4))) float f32x4;

__device__ __forceinline__ unsigned short f2bf(float f) {
    union { float f; unsigned u; } v; v.f = f;
    unsigned r = v.u + 0x7FFF + ((v.u >> 16) & 1);   // round-to-nearest-even
    return (unsigned short)(r >> 16);
}
__device__ __forceinline__ float bf2f(unsigned short s) {
    union { unsigned u; float f; } v; v.u = ((unsigned)s) << 16;
    return v.f;
}

// async global->LDS, 16B per lane; lds dst must be wave-uniform (lane*16 implicit)
#define GLDS16(g, l) __builtin_amdgcn_global_load_lds( \
    (const __attribute__((address_space(1))) void*)(g), \
    (__attribute__((address_space(3))) void*)(l), 16, 0, 0)

__device__ __forceinline__ void fma4(float4& d, float s, const float4& v) {
    d.x = fmaf(s, v.x, d.x);
    d.y = fmaf(s, v.y, d.y);
    d.z = fmaf(s, v.z, d.z);
    d.w = fmaf(s, v.w, d.w);
}

// ---------------- K1: E = emb_table[node_ids] (f32) ----------------
__global__ void k_gather(const float* __restrict__ emb, const int* __restrict__ ids,
                         float* __restrict__ E) {
    int n = blockIdx.x;
    int e = threadIdx.x;          // 64 threads
    int id = ids[n];
    id = id < 0 ? 0 : (id >= NN ? NN - 1 : id);
    E[(size_t)n * ED + e] = emb[(size_t)id * ED + e];
}

// ---------------- K2a: logits = relu(E E^T) -> bf16 ----------------
__global__ __launch_bounds__(256) void k_logits(const float* __restrict__ E,
                                                unsigned short* __restrict__ adjbf) {
    __shared__ __align__(16) float Ea[ED][64 + 4];   // transposed: Ea[k][row]
    __shared__ __align__(16) float Eb[ED][64 + 4];
    const int tid = threadIdx.x;
    const int ty = tid >> 4, tx = tid & 15;
    const int rb = blockIdx.x, cb = blockIdx.y;

    #pragma unroll
    for (int k = 0; k < 4; ++k) {
        int l = tid + k * 256;
        int row = l >> 4;
        int kq = (l & 15) * 4;
        float4 va = *(const float4*)&E[(size_t)(rb * 64 + row) * ED + kq];
        Ea[kq + 0][row] = va.x; Ea[kq + 1][row] = va.y;
        Ea[kq + 2][row] = va.z; Ea[kq + 3][row] = va.w;
        float4 vb = *(const float4*)&E[(size_t)(cb * 64 + row) * ED + kq];
        Eb[kq + 0][row] = vb.x; Eb[kq + 1][row] = vb.y;
        Eb[kq + 2][row] = vb.z; Eb[kq + 3][row] = vb.w;
    }
    __syncthreads();

    float4 acc[4] = {};
    #pragma unroll
    for (int k = 0; k < ED; ++k) {
        float4 ar = *(const float4*)&Ea[k][ty * 4];
        float4 br = *(const float4*)&Eb[k][tx * 4];
        fma4(acc[0], ar.x, br);
        fma4(acc[1], ar.y, br);
        fma4(acc[2], ar.z, br);
        fma4(acc[3], ar.w, br);
    }

    #pragma unroll
    for (int i = 0; i < 4; ++i) {
        float4 v = acc[i];
        ushort4 s;
        s.x = f2bf(fmaxf(v.x, 0.f)); s.y = f2bf(fmaxf(v.y, 0.f));
        s.z = f2bf(fmaxf(v.z, 0.f)); s.w = f2bf(fmaxf(v.w, 0.f));
        size_t n = (size_t)(rb * 64 + ty * 4 + i);
        *(ushort4*)&adjbf[n * NN + cb * 64 + tx * 4] = s;
    }
}

// ---------------- K2b: row softmax, bf16 in-place (single pass/row) ----------------
__global__ __launch_bounds__(256) void k_softmax(unsigned short* __restrict__ adj) {
    __shared__ float red[256];
    const int tid = threadIdx.x;
    const size_t base = (size_t)blockIdx.x * NN + (size_t)tid * 16;

    unsigned short t16[16];
    *(uint4*)&t16[0] = *(const uint4*)&adj[base];
    *(uint4*)&t16[8] = *(const uint4*)&adj[base + 8];
    float v[16];
    float mx = 0.0f;                      // relu >= 0
    #pragma unroll
    for (int j = 0; j < 16; ++j) { v[j] = bf2f(t16[j]); mx = fmaxf(mx, v[j]); }

    red[tid] = mx; __syncthreads();
    for (int off = 128; off > 0; off >>= 1) {
        if (tid < off) red[tid] = fmaxf(red[tid], red[tid + off]);
        __syncthreads();
    }
    mx = red[0];
    __syncthreads();

    float s = 0.f;
    #pragma unroll
    for (int j = 0; j < 16; ++j) { v[j] = expf(v[j] - mx); s += v[j]; }
    red[tid] = s; __syncthreads();
    for (int off = 128; off > 0; off >>= 1) {
        if (tid < off) red[tid] += red[tid + off];
        __syncthreads();
    }
    const float inv = 1.0f / red[0];

    #pragma unroll
    for (int j = 0; j < 16; ++j) t16[j] = f2bf(v[j] * inv);
    *(uint4*)&adj[base]     = *(const uint4*)&t16[0];
    *(uint4*)&adj[base + 8] = *(const uint4*)&t16[8];
}

// ---------------- K3: WT[m][k] = bf16(W[k][m]) ----------------
__global__ void k_wt(const float* __restrict__ W, unsigned short* __restrict__ WT) {
    int m = blockIdx.x;    // dout
    int k = threadIdx.x;   // din
    WT[(size_t)m * DIN + k] = f2bf(W[(size_t)k * DOUT + m]);
}

// ---------------- K4: yT[b][dout][node] = bf16( (x@W)^T ) ----------------
// MFMA GEMM: M=DOUT, N=NN(node), K=DIN. A=WT [M][K] bf16; B^T = x[b] [N][K] f32->bf16.
__global__ __launch_bounds__(256) void k_y(const unsigned short* __restrict__ WT,
                                           const float* __restrict__ x,
                                           unsigned short* __restrict__ yT) {
    __shared__ __align__(16) short As[128 * 32];
    __shared__ __align__(16) short Bs[128 * 32];
    const int tid = threadIdx.x;
    const int lane = tid & 63, w = tid >> 6;
    const int wr = (w >> 1) * 64, wc = (w & 1) * 64;
    const int fr = lane & 15, fq = lane >> 4;
    const int m0 = blockIdx.x * 128;   // dout tile
    const int n0 = blockIdx.y * 128;   // node tile
    const int b  = blockIdx.z;
    const float* xb = x + (size_t)b * NN * DIN;
    const int brow = tid >> 1, bh = (tid & 1) * 16;   // B staging: row, k-half

    f32x4 acc[4][4];
    #pragma unroll
    for (int i = 0; i < 4; ++i)
        #pragma unroll
        for (int j = 0; j < 4; ++j) acc[i][j] = (f32x4){0.f, 0.f, 0.f, 0.f};

    for (int k0 = 0; k0 < DIN; k0 += 32) {
        __syncthreads();
        // A tile via global_load_lds (bf16, 16B/lane, 2 issues/wave)
        #pragma unroll
        for (int i = 0; i < 2; ++i) {
            int idx = (w * 2 + i) * 512 + lane * 8;
            int row = idx >> 5, kk = idx & 31;
            GLDS16(WT + (size_t)(m0 + row) * DIN + k0 + kk, &As[(w * 2 + i) * 512]);
        }
        // B tile: f32 read + convert + ds_write (16 values/thread)
        float fv[16];
        *(float4*)&fv[0]  = *(const float4*)&xb[(size_t)(n0 + brow) * DIN + k0 + bh + 0];
        *(float4*)&fv[4]  = *(const float4*)&xb[(size_t)(n0 + brow) * DIN + k0 + bh + 4];
        *(float4*)&fv[8]  = *(const float4*)&xb[(size_t)(n0 + brow) * DIN + k0 + bh + 8];
        *(float4*)&fv[12] = *(const float4*)&xb[(size_t)(n0 + brow) * DIN + k0 + bh + 12];
        unsigned u[8];
        #pragma unroll
        for (int j = 0; j < 8; ++j)
            u[j] = (unsigned)f2bf(fv[2 * j]) | ((unsigned)f2bf(fv[2 * j + 1]) << 16);
        *(uint4*)&Bs[brow * 32 + bh]     = make_uint4(u[0], u[1], u[2], u[3]);
        *(uint4*)&Bs[brow * 32 + bh + 8] = make_uint4(u[4], u[5], u[6], u[7]);
        __syncthreads();

        bf16x8 a[4], bb[4];
        #pragma unroll
        for (int mi = 0; mi < 4; ++mi)
            a[mi] = *(const bf16x8*)&As[(wr + mi * 16 + fr) * 32 + fq * 8];
        #pragma unroll
        for (int ni = 0; ni < 4; ++ni)
            bb[ni] = *(const bf16x8*)&Bs[(wc + ni * 16 + fr) * 32 + fq * 8];
        #pragma unroll
        for (int mi = 0; mi < 4; ++mi)
            #pragma unroll
            for (int ni = 0; ni < 4; ++ni)
                acc[mi][ni] = __builtin_amdgcn_mfma_f32_16x16x32_bf16(
                    a[mi], bb[ni], acc[mi][ni], 0, 0, 0);
    }

    unsigned short* yb = yT + (size_t)b * DOUT * NN;
    #pragma unroll
    for (int mi = 0; mi < 4; ++mi)
        #pragma unroll
        for (int ni = 0; ni < 4; ++ni)
            #pragma unroll
            for (int r = 0; r < 4; ++r) {
                int row = m0 + wr + mi * 16 + fq * 4 + r;   // dout
                int col = n0 + wc + ni * 16 + fr;           // node
                yb[(size_t)row * NN + col] = f2bf(acc[mi][ni][r]);
            }
}

// ---------------- K5: out = relu(adj @ y + b) ----------------
// M=NN(node), N=DOUT, K=NN. A=adj [M][K] bf16; B^T = yT[b] [N][K] bf16.
__global__ __launch_bounds__(256) void k_gcn(const unsigned short* __restrict__ adj,
                                             const unsigned short* __restrict__ yT,
                                             const float* __restrict__ bias,
                                             float* __restrict__ out) {
    __shared__ __align__(16) short As[128 * 32];
    __shared__ __align__(16) short Bs[128 * 32];
    const int tid = threadIdx.x;
    const int lane = tid & 63, w = tid >> 6;
    const int wr = (w >> 1) * 64, wc = (w & 1) * 64;
    const int fr = lane & 15, fq = lane >> 4;
    const int m0 = blockIdx.x * 128;   // node tile
    const int n0 = blockIdx.y * 128;   // dout tile
    const int b  = blockIdx.z;
    const unsigned short* yb = yT + (size_t)b * DOUT * NN;

    f32x4 acc[4][4];
    #pragma unroll
    for (int i = 0; i < 4; ++i)
        #pragma unroll
        for (int j = 0; j < 4; ++j) acc[i][j] = (f32x4){0.f, 0.f, 0.f, 0.f};

    for (int k0 = 0; k0 < NN; k0 += 32) {
        __syncthreads();
        #pragma unroll
        for (int i = 0; i < 2; ++i) {
            int idx = (w * 2 + i) * 512 + lane * 8;
            int row = idx >> 5, kk = idx & 31;
            GLDS16(adj + (size_t)(m0 + row) * NN + k0 + kk, &As[(w * 2 + i) * 512]);
            GLDS16(yb  + (size_t)(n0 + row) * NN + k0 + kk, &Bs[(w * 2 + i) * 512]);
        }
        __syncthreads();

        bf16x8 a[4], bb[4];
        #pragma unroll
        for (int mi = 0; mi < 4; ++mi)
            a[mi] = *(const bf16x8*)&As[(wr + mi * 16 + fr) * 32 + fq * 8];
        #pragma unroll
        for (int ni = 0; ni < 4; ++ni)
            bb[ni] = *(const bf16x8*)&Bs[(wc + ni * 16 + fr) * 32 + fq * 8];
        #pragma unroll
        for (int mi = 0; mi < 4; ++mi)
            #pragma unroll
            for (int ni = 0; ni < 4; ++ni)
                acc[mi][ni] = __builtin_amdgcn_mfma_f32_16x16x32_bf16(
                    a[mi], bb[ni], acc[mi][ni], 0, 0, 0);
    }

    float bv[4];
    #pragma unroll
    for (int ni = 0; ni < 4; ++ni) bv[ni] = bias[n0 + wc + ni * 16 + fr];

    #pragma unroll
    for (int mi = 0; mi < 4; ++mi)
        #pragma unroll
        for (int ni = 0; ni < 4; ++ni)
            #pragma unroll
            for (int r = 0; r < 4; ++r) {
                int row = m0 + wr + mi * 16 + fq * 4 + r;   // node
                int col = n0 + wc + ni * 16 + fr;           // dout
                float vv = acc[mi][ni][r] + bv[ni];
                out[((size_t)b * NN + row) * DOUT + col] = fmaxf(vv, 0.f);
            }
}

extern "C" void kernel_launch(void* const* d_in, const int* in_sizes, int n_in,
                              void* d_out, int out_size, void* d_ws, size_t ws_size,
                              hipStream_t stream) {
    const float* x    = (const float*)d_in[0];
    const int*   ids  = (const int*)d_in[1];
    const float* emb  = (const float*)d_in[2];
    const float* W    = (const float*)d_in[3];
    const float* bias = (const float*)d_in[4];
    float* out = (float*)d_out;

    // workspace layout (97.1 MiB total)
    char* ws = (char*)d_ws;
    unsigned short* adjbf = (unsigned short*)ws;                          // 32 MiB
    float*          E     = (float*)(ws + 33554432);                      // 1 MiB
    unsigned short* WT    = (unsigned short*)(ws + 33554432 + 1048576);   // 128 KiB
    unsigned short* yT    = (unsigned short*)(ws + 33554432 + 1048576 + 131072); // 64 MiB

    k_gather  <<<NN, ED, 0, stream>>>(emb, ids, E);
    k_logits  <<<dim3(NN / 64, NN / 64), 256, 0, stream>>>(E, adjbf);
    k_softmax <<<NN, 256, 0, stream>>>(adjbf);
    k_wt      <<<DOUT, DIN, 0, stream>>>(W, WT);
    k_y       <<<dim3(DOUT / 128, NN / 128, NB), 256, 0, stream>>>(WT, x, yT);
    k_gcn     <<<dim3(NN / 128, DOUT / 128, NB), 256, 0, stream>>>(adjbf, yT, bias, out);
}

// Round 6
// 338.844 us; speedup vs baseline: 9.9388x; 1.2509x over previous
//
#include <hip/hip_runtime.h>

#define NN   4096   // nodes
#define ED   64     // embed dim
#define DIN  256    // in_dim
#define DOUT 256    // out_dim
#define NB   32     // batch

typedef __attribute__((ext_vector_type(8))) short bf16x8;
typedef __attribute__((ext_vector_type(4))) float f32x4;

__device__ __forceinline__ unsigned short f2bf(float f) {
    union { float f; unsigned u; } v; v.f = f;
    unsigned r = v.u + 0x7FFF + ((v.u >> 16) & 1);   // round-to-nearest-even
    return (unsigned short)(r >> 16);
}
__device__ __forceinline__ float bf2f(unsigned short s) {
    union { unsigned u; float f; } v; v.u = ((unsigned)s) << 16;
    return v.f;
}

// async global->LDS, 16B per lane; lds dst must be wave-uniform (lane*16 implicit)
#define GLDS16(g, l) __builtin_amdgcn_global_load_lds( \
    (const __attribute__((address_space(1))) void*)(g), \
    (__attribute__((address_space(3))) void*)(l), 16, 0, 0)

__device__ __forceinline__ void fma4(float4& d, float s, const float4& v) {
    d.x = fmaf(s, v.x, d.x);
    d.y = fmaf(s, v.y, d.y);
    d.z = fmaf(s, v.z, d.z);
    d.w = fmaf(s, v.w, d.w);
}

// ---------------- K1: E = emb_table[node_ids] (f32) ----------------
__global__ void k_gather(const float* __restrict__ emb, const int* __restrict__ ids,
                         float* __restrict__ E) {
    int n = blockIdx.x;
    int e = threadIdx.x;          // 64 threads
    int id = ids[n];
    id = id < 0 ? 0 : (id >= NN ? NN - 1 : id);
    E[(size_t)n * ED + e] = emb[(size_t)id * ED + e];
}

// ---------------- K2a: logits = relu(E E^T) -> bf16 ----------------
__global__ __launch_bounds__(256) void k_logits(const float* __restrict__ E,
                                                unsigned short* __restrict__ adjbf) {
    __shared__ __align__(16) float Ea[ED][64 + 4];   // transposed: Ea[k][row]
    __shared__ __align__(16) float Eb[ED][64 + 4];
    const int tid = threadIdx.x;
    const int ty = tid >> 4, tx = tid & 15;
    const int rb = blockIdx.x, cb = blockIdx.y;

    #pragma unroll
    for (int k = 0; k < 4; ++k) {
        int l = tid + k * 256;
        int row = l >> 4;
        int kq = (l & 15) * 4;
        float4 va = *(const float4*)&E[(size_t)(rb * 64 + row) * ED + kq];
        Ea[kq + 0][row] = va.x; Ea[kq + 1][row] = va.y;
        Ea[kq + 2][row] = va.z; Ea[kq + 3][row] = va.w;
        float4 vb = *(const float4*)&E[(size_t)(cb * 64 + row) * ED + kq];
        Eb[kq + 0][row] = vb.x; Eb[kq + 1][row] = vb.y;
        Eb[kq + 2][row] = vb.z; Eb[kq + 3][row] = vb.w;
    }
    __syncthreads();

    float4 acc[4] = {};
    #pragma unroll
    for (int k = 0; k < ED; ++k) {
        float4 ar = *(const float4*)&Ea[k][ty * 4];
        float4 br = *(const float4*)&Eb[k][tx * 4];
        fma4(acc[0], ar.x, br);
        fma4(acc[1], ar.y, br);
        fma4(acc[2], ar.z, br);
        fma4(acc[3], ar.w, br);
    }

    #pragma unroll
    for (int i = 0; i < 4; ++i) {
        float4 v = acc[i];
        ushort4 s;
        s.x = f2bf(fmaxf(v.x, 0.f)); s.y = f2bf(fmaxf(v.y, 0.f));
        s.z = f2bf(fmaxf(v.z, 0.f)); s.w = f2bf(fmaxf(v.w, 0.f));
        size_t n = (size_t)(rb * 64 + ty * 4 + i);
        *(ushort4*)&adjbf[n * NN + cb * 64 + tx * 4] = s;
    }
}

// ---------------- K2b: row softmax, bf16 in-place (single pass/row) ----------------
__global__ __launch_bounds__(256) void k_softmax(unsigned short* __restrict__ adj) {
    __shared__ float red[256];
    const int tid = threadIdx.x;
    const size_t base = (size_t)blockIdx.x * NN + (size_t)tid * 16;

    unsigned short t16[16];
    *(uint4*)&t16[0] = *(const uint4*)&adj[base];
    *(uint4*)&t16[8] = *(const uint4*)&adj[base + 8];
    float v[16];
    float mx = 0.0f;                      // relu >= 0
    #pragma unroll
    for (int j = 0; j < 16; ++j) { v[j] = bf2f(t16[j]); mx = fmaxf(mx, v[j]); }

    red[tid] = mx; __syncthreads();
    for (int off = 128; off > 0; off >>= 1) {
        if (tid < off) red[tid] = fmaxf(red[tid], red[tid + off]);
        __syncthreads();
    }
    mx = red[0];
    __syncthreads();

    float s = 0.f;
    #pragma unroll
    for (int j = 0; j < 16; ++j) { v[j] = expf(v[j] - mx); s += v[j]; }
    red[tid] = s; __syncthreads();
    for (int off = 128; off > 0; off >>= 1) {
        if (tid < off) red[tid] += red[tid + off];
        __syncthreads();
    }
    const float inv = 1.0f / red[0];

    #pragma unroll
    for (int j = 0; j < 16; ++j) t16[j] = f2bf(v[j] * inv);
    *(uint4*)&adj[base]     = *(const uint4*)&t16[0];
    *(uint4*)&adj[base + 8] = *(const uint4*)&t16[8];
}

// ---------------- K3: WT[m][k] = bf16(W[k][m]) ----------------
__global__ void k_wt(const float* __restrict__ W, unsigned short* __restrict__ WT) {
    int m = blockIdx.x;    // dout
    int k = threadIdx.x;   // din
    WT[(size_t)m * DIN + k] = f2bf(W[(size_t)k * DOUT + m]);
}

// ---------------- K4: yT[b][dout][node] = bf16( (x@W)^T ) ----------------
// MFMA GEMM: M=DOUT, N=NN(node), K=DIN. A=WT [M][K] bf16; B^T = x[b] [N][K] f32->bf16.
__global__ __launch_bounds__(256) void k_y(const unsigned short* __restrict__ WT,
                                           const float* __restrict__ x,
                                           unsigned short* __restrict__ yT) {
    __shared__ __align__(16) short As[128 * 32];
    __shared__ __align__(16) short Bs[128 * 32];
    const int tid = threadIdx.x;
    const int lane = tid & 63, w = tid >> 6;
    const int wr = (w >> 1) * 64, wc = (w & 1) * 64;
    const int fr = lane & 15, fq = lane >> 4;
    const int m0 = blockIdx.x * 128;   // dout tile
    const int n0 = blockIdx.y * 128;   // node tile
    const int b  = blockIdx.z;
    const float* xb = x + (size_t)b * NN * DIN;
    const int brow = tid >> 1, bh = (tid & 1) * 16;   // B staging: row, k-half

    f32x4 acc[4][4];
    #pragma unroll
    for (int i = 0; i < 4; ++i)
        #pragma unroll
        for (int j = 0; j < 4; ++j) acc[i][j] = (f32x4){0.f, 0.f, 0.f, 0.f};

    for (int k0 = 0; k0 < DIN; k0 += 32) {
        __syncthreads();
        // A tile via global_load_lds (bf16, 16B/lane, 2 issues/wave)
        #pragma unroll
        for (int i = 0; i < 2; ++i) {
            int idx = (w * 2 + i) * 512 + lane * 8;
            int row = idx >> 5, kk = idx & 31;
            GLDS16(WT + (size_t)(m0 + row) * DIN + k0 + kk, &As[(w * 2 + i) * 512]);
        }
        // B tile: f32 read + convert + ds_write (16 values/thread)
        float fv[16];
        *(float4*)&fv[0]  = *(const float4*)&xb[(size_t)(n0 + brow) * DIN + k0 + bh + 0];
        *(float4*)&fv[4]  = *(const float4*)&xb[(size_t)(n0 + brow) * DIN + k0 + bh + 4];
        *(float4*)&fv[8]  = *(const float4*)&xb[(size_t)(n0 + brow) * DIN + k0 + bh + 8];
        *(float4*)&fv[12] = *(const float4*)&xb[(size_t)(n0 + brow) * DIN + k0 + bh + 12];
        unsigned u[8];
        #pragma unroll
        for (int j = 0; j < 8; ++j)
            u[j] = (unsigned)f2bf(fv[2 * j]) | ((unsigned)f2bf(fv[2 * j + 1]) << 16);
        *(uint4*)&Bs[brow * 32 + bh]     = make_uint4(u[0], u[1], u[2], u[3]);
        *(uint4*)&Bs[brow * 32 + bh + 8] = make_uint4(u[4], u[5], u[6], u[7]);
        __syncthreads();

        bf16x8 a[4], bb[4];
        #pragma unroll
        for (int mi = 0; mi < 4; ++mi)
            a[mi] = *(const bf16x8*)&As[(wr + mi * 16 + fr) * 32 + fq * 8];
        #pragma unroll
        for (int ni = 0; ni < 4; ++ni)
            bb[ni] = *(const bf16x8*)&Bs[(wc + ni * 16 + fr) * 32 + fq * 8];
        #pragma unroll
        for (int mi = 0; mi < 4; ++mi)
            #pragma unroll
            for (int ni = 0; ni < 4; ++ni)
                acc[mi][ni] = __builtin_amdgcn_mfma_f32_16x16x32_bf16(
                    a[mi], bb[ni], acc[mi][ni], 0, 0, 0);
    }

    unsigned short* yb = yT + (size_t)b * DOUT * NN;
    #pragma unroll
    for (int mi = 0; mi < 4; ++mi)
        #pragma unroll
        for (int ni = 0; ni < 4; ++ni)
            #pragma unroll
            for (int r = 0; r < 4; ++r) {
                int row = m0 + wr + mi * 16 + fq * 4 + r;   // dout
                int col = n0 + wc + ni * 16 + fr;           // node
                yb[(size_t)row * NN + col] = f2bf(acc[mi][ni][r]);
            }
}

// ---------------- K5: big GEMM, 256^2 tile, 8-wave, 4-phase/K-tile, counted vmcnt ----
// C[4096 x 8192] = adj[4096 x 4096] @ Y[4096 x 8192], Y^T = yT flat [8192][4096].
// out[b][node][dout] = relu(C[node][b*256+dout] + bias[dout]).
// grid (16, 32): bx = m-tile (node), by = batch (n-range b*256..b*256+255).
__global__ __launch_bounds__(512, 2) void k_gcn(const unsigned short* __restrict__ adj,
                                                const unsigned short* __restrict__ yT,
                                                const float* __restrict__ bias,
                                                float* __restrict__ out) {
    __shared__ __align__(16) char smem[131072];   // 2 bufs x (A 32K + B 32K)

    const int tid  = threadIdx.x;
    const int lane = tid & 63, wid = tid >> 6;    // 8 waves
    const int fr = lane & 15, fq = lane >> 4;
    const int wr = wid >> 2, wc = wid & 3;        // 2 M-waves x 4 N-waves
    const int m0 = blockIdx.x * 256;              // node tile base
    const int by = blockIdx.y;                    // batch

    const char* Apanel = (const char*)(adj + (size_t)m0 * NN);          // row stride 8192 B
    const char* Bpanel = (const char*)(yT + (size_t)by * DOUT * NN);    // rows = dout 0..255

    // ---- staging: one tile-half matrix (256 rows x 64 k bf16 = 32KB) in 4 calls/thread.
    // LDS linear dest; source column pre-swizzled with the SAME involution used on reads:
    //   byte ^= ((row & 7) << 4)   (permutes 16B chunks within a 128B row)
    #define STAGE4(gpan, ktb, ldsb)                                              \
        {                                                                        \
            _Pragma("unroll")                                                    \
            for (int c = 0; c < 4; ++c) {                                        \
                int bo  = c * 8192 + wid * 1024 + lane * 16;                     \
                int row = bo >> 7;                                               \
                int scol = (bo & 127) ^ ((row & 7) << 4);                        \
                GLDS16((gpan) + (size_t)row * 8192 + (ktb) + scol,               \
                       (ldsb) + c * 8192 + wid * 1024);                          \
            }                                                                    \
        }

    // prologue: stage tiles 0 and 1 (B then A per tile, matching steady-state FIFO order)
    STAGE4(Bpanel, 0,   smem + 32768);
    STAGE4(Apanel, 0,   smem);
    STAGE4(Bpanel, 128, smem + 65536 + 32768);
    STAGE4(Apanel, 128, smem + 65536);

    f32x4 acc[8][4];
    #pragma unroll
    for (int i = 0; i < 8; ++i)
        #pragma unroll
        for (int j = 0; j < 4; ++j) acc[i][j] = (f32x4){0.f, 0.f, 0.f, 0.f};

    // per-lane read bases (swizzled)
    const int xorp0 = (fq << 4) ^ ((fr & 7) << 4);          // ks=0 column bytes
    const int xorp1 = (64 | (fq << 4)) ^ ((fr & 7) << 4);   // ks=1 column bytes
    const int abase = (wr * 128 + fr) * 128;                // + am*2048 + xorp
    const int bbase = (wc * 64 + fr) * 128;                 // + ni*2048 + xorp

    bf16x8 Ar[4][2], Br[4][2];

    for (int j = 0; j < 64; ++j) {
        const int cur = j & 1;
        char* bufA = smem + cur * 65536;
        char* bufB = bufA + 32768;

        // counted wait: tile j's 8 loads landed; tile j+1's 8 stay in flight
        if (j + 1 < 64) { asm volatile("s_waitcnt vmcnt(8)" ::: "memory"); }
        else            { asm volatile("s_waitcnt vmcnt(0)" ::: "memory"); }
        __builtin_amdgcn_sched_barrier(0);
        __builtin_amdgcn_s_barrier();     // staged tile visible to all waves

        // ---- P0: read A(mh0) + B(ni 0,1)
        #pragma unroll
        for (int mi = 0; mi < 4; ++mi) {
            Ar[mi][0] = *(const bf16x8*)(bufA + abase + mi * 2048 + xorp0);
            Ar[mi][1] = *(const bf16x8*)(bufA + abase + mi * 2048 + xorp1);
        }
        #pragma unroll
        for (int ni = 0; ni < 2; ++ni) {
            Br[ni][0] = *(const bf16x8*)(bufB + bbase + ni * 2048 + xorp0);
            Br[ni][1] = *(const bf16x8*)(bufB + bbase + ni * 2048 + xorp1);
        }
        __builtin_amdgcn_s_barrier();
        asm volatile("s_waitcnt lgkmcnt(0)" ::: "memory");
        __builtin_amdgcn_sched_barrier(0);
        __builtin_amdgcn_s_setprio(1);
        #pragma unroll
        for (int mi = 0; mi < 4; ++mi)
            #pragma unroll
            for (int ni = 0; ni < 2; ++ni) {
                acc[mi][ni] = __builtin_amdgcn_mfma_f32_16x16x32_bf16(Ar[mi][0], Br[ni][0], acc[mi][ni], 0, 0, 0);
                acc[mi][ni] = __builtin_amdgcn_mfma_f32_16x16x32_bf16(Ar[mi][1], Br[ni][1], acc[mi][ni], 0, 0, 0);
            }
        __builtin_amdgcn_s_setprio(0);
        __builtin_amdgcn_s_barrier();

        // ---- P1: read B(ni 2,3)
        #pragma unroll
        for (int ni = 2; ni < 4; ++ni) {
            Br[ni][0] = *(const bf16x8*)(bufB + bbase + ni * 2048 + xorp0);
            Br[ni][1] = *(const bf16x8*)(bufB + bbase + ni * 2048 + xorp1);
        }
        __builtin_amdgcn_s_barrier();
        asm volatile("s_waitcnt lgkmcnt(0)" ::: "memory");
        __builtin_amdgcn_sched_barrier(0);
        __builtin_amdgcn_s_setprio(1);
        #pragma unroll
        for (int mi = 0; mi < 4; ++mi)
            #pragma unroll
            for (int ni = 2; ni < 4; ++ni) {
                acc[mi][ni] = __builtin_amdgcn_mfma_f32_16x16x32_bf16(Ar[mi][0], Br[ni][0], acc[mi][ni], 0, 0, 0);
                acc[mi][ni] = __builtin_amdgcn_mfma_f32_16x16x32_bf16(Ar[mi][1], Br[ni][1], acc[mi][ni], 0, 0, 0);
            }
        __builtin_amdgcn_s_setprio(0);
        __builtin_amdgcn_s_barrier();

        // ---- P2: read A(mh1); issue (j+2).B into this buf's B (B-reads of tile j done)
        #pragma unroll
        for (int mi = 0; mi < 4; ++mi) {
            Ar[mi][0] = *(const bf16x8*)(bufA + abase + 8192 + mi * 2048 + xorp0);
            Ar[mi][1] = *(const bf16x8*)(bufA + abase + 8192 + mi * 2048 + xorp1);
        }
        if (j + 2 < 64) STAGE4(Bpanel, (j + 2) * 128, bufB);
        __builtin_amdgcn_s_barrier();
        asm volatile("s_waitcnt lgkmcnt(0)" ::: "memory");
        __builtin_amdgcn_sched_barrier(0);
        __builtin_amdgcn_s_setprio(1);
        #pragma unroll
        for (int mi = 0; mi < 4; ++mi)
            #pragma unroll
            for (int ni = 0; ni < 2; ++ni) {
                acc[4 + mi][ni] = __builtin_amdgcn_mfma_f32_16x16x32_bf16(Ar[mi][0], Br[ni][0], acc[4 + mi][ni], 0, 0, 0);
                acc[4 + mi][ni] = __builtin_amdgcn_mfma_f32_16x16x32_bf16(Ar[mi][1], Br[ni][1], acc[4 + mi][ni], 0, 0, 0);
            }
        __builtin_amdgcn_s_setprio(0);
        __builtin_amdgcn_s_barrier();

        // ---- P3: issue (j+2).A (A-reads of tile j done); MFMA from registers
        if (j + 2 < 64) STAGE4(Apanel, (j + 2) * 128, bufA);
        __builtin_amdgcn_s_setprio(1);
        #pragma unroll
        for (int mi = 0; mi < 4; ++mi)
            #pragma unroll
            for (int ni = 2; ni < 4; ++ni) {
                acc[4 + mi][ni] = __builtin_amdgcn_mfma_f32_16x16x32_bf16(Ar[mi][0], Br[ni][0], acc[4 + mi][ni], 0, 0, 0);
                acc[4 + mi][ni] = __builtin_amdgcn_mfma_f32_16x16x32_bf16(Ar[mi][1], Br[ni][1], acc[4 + mi][ni], 0, 0, 0);
            }
        __builtin_amdgcn_s_setprio(0);
        // no closing barrier: next iteration's vmcnt + tile-open barrier covers it
    }

    // ---- epilogue: bias + relu, scatter to out[b][node][dout]
    float bv[4];
    #pragma unroll
    for (int ni = 0; ni < 4; ++ni) bv[ni] = bias[wc * 64 + ni * 16 + fr];

    #pragma unroll
    for (int am = 0; am < 8; ++am) {
        const int node = m0 + wr * 128 + am * 16 + fq * 4;
        #pragma unroll
        for (int ni = 0; ni < 4; ++ni) {
            const int dcol = wc * 64 + ni * 16 + fr;
            #pragma unroll
            for (int rr = 0; rr < 4; ++rr) {
                float vv = acc[am][ni][rr] + bv[ni];
                out[((size_t)by * NN + node + rr) * DOUT + dcol] = fmaxf(vv, 0.f);
            }
        }
    }
    #undef STAGE4
}

extern "C" void kernel_launch(void* const* d_in, const int* in_sizes, int n_in,
                              void* d_out, int out_size, void* d_ws, size_t ws_size,
                              hipStream_t stream) {
    const float* x    = (const float*)d_in[0];
    const int*   ids  = (const int*)d_in[1];
    const float* emb  = (const float*)d_in[2];
    const float* W    = (const float*)d_in[3];
    const float* bias = (const float*)d_in[4];
    float* out = (float*)d_out;

    // workspace layout (97.1 MiB total)
    char* ws = (char*)d_ws;
    unsigned short* adjbf = (unsigned short*)ws;                          // 32 MiB
    float*          E     = (float*)(ws + 33554432);                      // 1 MiB
    unsigned short* WT    = (unsigned short*)(ws + 33554432 + 1048576);   // 128 KiB
    unsigned short* yT    = (unsigned short*)(ws + 33554432 + 1048576 + 131072); // 64 MiB

    k_gather  <<<NN, ED, 0, stream>>>(emb, ids, E);
    k_logits  <<<dim3(NN / 64, NN / 64), 256, 0, stream>>>(E, adjbf);
    k_softmax <<<NN, 256, 0, stream>>>(adjbf);
    k_wt      <<<DOUT, DIN, 0, stream>>>(W, WT);
    k_y       <<<dim3(DOUT / 128, NN / 128, NB), 256, 0, stream>>>(WT, x, yT);
    k_gcn     <<<dim3(16, 32), 512, 0, stream>>>(adjbf, yT, bias, out);
}